// Round 11
// baseline (588.769 us; speedup 1.0000x reference)
//
#include <hip/hip_runtime.h>

#define GG 256

typedef __bf16 bf16x8 __attribute__((ext_vector_type(8)));
typedef __bf16 bf16x4 __attribute__((ext_vector_type(4)));
typedef float floatx4 __attribute__((ext_vector_type(4)));
typedef float f32x2 __attribute__((ext_vector_type(2)));

__device__ __forceinline__ float lrelu(float x) { return x > 0.f ? x : 0.2f * x; }

// ---- fused weight prep ----
__device__ __forceinline__ void wt1(const float* __restrict__ B, __bf16* __restrict__ Bt,
                                    int K, int M, int idx) {
    int k = idx / M, m = idx - k * M;
    Bt[(size_t)m * K + k] = (__bf16)B[idx];
}
__device__ __forceinline__ void wattn1(const float* __restrict__ W,
                                       const float* __restrict__ as_,
                                       const float* __restrict__ ad_,
                                       __bf16* __restrict__ dst, int K, int C, int idx) {
    int j = idx / K, k = idx - j * K;
    float v = 0.f;
    if (j < 8) {
        int h = j & 3;
        const float* att = (j < 4) ? as_ : ad_;
        int M = 4 * C;
        for (int c = 0; c < C; c++) v += W[(size_t)k * M + h * C + c] * att[h * C + c];
    }
    dst[(size_t)j * K + k] = (__bf16)v;
}

__global__ void k_wprep(const float* W1, const float* lw1, const float* as1, const float* ad1,
                        const float* W2, const float* lw2, const float* as2, const float* ad2,
                        const float* W3, const float* lw3, const float* as3, const float* ad3,
                        __bf16* B1t, __bf16* B2t, __bf16* B3t) {
    int idx = blockIdx.x * blockDim.x + threadIdx.x;
    if (idx < 32768) { wt1(W1, B1t, 128, 256, idx); return; }
    idx -= 32768;
    if (idx < 32768) { wt1(lw1, B1t + 256 * 128, 128, 256, idx); return; }
    idx -= 32768;
    if (idx < 2048) { wattn1(W1, as1, ad1, B1t + 512 * 128, 128, 64, idx); return; }
    idx -= 2048;
    if (idx < 65536) { wt1(W2, B2t, 256, 256, idx); return; }
    idx -= 65536;
    if (idx < 65536) { wt1(lw2, B2t + 256 * 256, 256, 256, idx); return; }
    idx -= 65536;
    if (idx < 4096) { wattn1(W2, as2, ad2, B2t + 512 * 256, 256, 64, idx); return; }
    idx -= 4096;
    if (idx < 131072) { wt1(W3, B3t, 256, 512, idx); return; }
    idx -= 131072;
    if (idx < 32768) { wt1(lw3, B3t + 512 * 256, 256, 128, idx); return; }
    idx -= 32768;
    if (idx < 4096) { wattn1(W3, as3, ad3, B3t + 640 * 256, 256, 128, idx); return; }
}

// 128-row-block GEMM, register-pipelined B staging. A (128 x K) staged in LDS once,
// A frags hoisted to regs (2 row-tiles/wave); per 64-col B tile: regs->LDS->MFMA with
// next tile prefetched into regs. cols<Mx -> fp8 bytes; [Mx,Mtot) -> lin
// (LINBF ? bf16 : fp32) +bias1(+bias2); mini-tile [Mtot,Mtot+16) -> a_s/a_d (y==1).
template <int K, bool EMB, bool LINBF>
__global__ __launch_bounds__(256) void k_gemm_all(const __bf16* __restrict__ A,
                                                  const int* __restrict__ xl,
                                                  const int* __restrict__ xr,
                                                  const float* __restrict__ emb,
                                                  const __bf16* __restrict__ Bt,
                                                  int n, int n1, int Mx, int Ml,
                                                  unsigned char* __restrict__ x8, int ldx,
                                                  float* __restrict__ linf,
                                                  __bf16* __restrict__ linb, int ldl,
                                                  const float* __restrict__ bias1,
                                                  const float* __restrict__ bias2,
                                                  float* __restrict__ a_s,
                                                  float* __restrict__ a_d) {
    constexpr int KS = K / 32;
    constexpr int LDK = K + 8;
    constexpr int LPR = K / 8;            // bf16x8 chunks per row
    constexpr int NCHA = 128 * LPR / 256; // A chunks per thread
    constexpr int NCHB = 64 * LPR / 256;  // B chunks per thread
    __shared__ __bf16 S[128 * LDK];
    int tid = threadIdx.x;
    int wave = tid >> 6, lane = tid & 63;
    int row0 = blockIdx.x * 128;
    // --- stage A (coalesced; optional fused embedding gather) ---
#pragma unroll
    for (int c = 0; c < NCHA; c++) {
        int i = tid + c * 256;
        int r = i / LPR, ko = (i - r * LPR) * 8;
        int gr = row0 + r;
        bf16x8 v = {};
        if (gr < n) {
            if (EMB) {
                int xi = (gr < n1) ? xl[gr] : xr[gr - n1];
                const float4* src = (const float4*)(emb + ((size_t)xi << 7) + ko);
                float4 q0 = src[0], q1 = src[1];
                v = bf16x8{(__bf16)q0.x, (__bf16)q0.y, (__bf16)q0.z, (__bf16)q0.w,
                           (__bf16)q1.x, (__bf16)q1.y, (__bf16)q1.z, (__bf16)q1.w};
            } else {
                v = *(const bf16x8*)(A + (size_t)gr * K + ko);
            }
        }
        *(bf16x8*)&S[r * LDK + ko] = v;
    }
    __syncthreads();
    int kOff = (lane >> 4) * 8;
    int colBase = lane & 15;
    bf16x8 af[2][KS];
#pragma unroll
    for (int rt = 0; rt < 2; rt++)
#pragma unroll
        for (int ks = 0; ks < KS; ks++)
            af[rt][ks] = *(const bf16x8*)&S[(wave * 32 + rt * 16 + colBase) * LDK + ks * 32 + kOff];
    int Mtot = Mx + Ml;
    int gr0 = row0 + wave * 32 + ((lane >> 4) << 2);
    int half = (Mtot / 128) * 64;
    int c0beg = blockIdx.y * half;
    int T = half / 64;
    bf16x8 regs[NCHB];
#pragma unroll
    for (int c = 0; c < NCHB; c++) {
        int i = tid + c * 256;
        int r = i / LPR, ko = (i - r * LPR) * 8;
        regs[c] = *(const bf16x8*)(Bt + (size_t)(c0beg + r) * K + ko);
    }
    for (int t = 0; t < T; t++) {
        __syncthreads();  // prior S readers (A hoist / prev MFMA) done
#pragma unroll
        for (int c = 0; c < NCHB; c++) {
            int i = tid + c * 256;
            int r = i / LPR, ko = (i - r * LPR) * 8;
            *(bf16x8*)&S[r * LDK + ko] = regs[c];
        }
        if (t + 1 < T) {
            int c0n = c0beg + (t + 1) * 64;
#pragma unroll
            for (int c = 0; c < NCHB; c++) {
                int i = tid + c * 256;
                int r = i / LPR, ko = (i - r * LPR) * 8;
                regs[c] = *(const bf16x8*)(Bt + (size_t)(c0n + r) * K + ko);
            }
        }
        __syncthreads();
        floatx4 acc[2][4] = {};
#pragma unroll
        for (int ct = 0; ct < 4; ct++) {
#pragma unroll
            for (int ks = 0; ks < KS; ks++) {
                bf16x8 bf = *(const bf16x8*)&S[(ct * 16 + colBase) * LDK + ks * 32 + kOff];
#pragma unroll
                for (int rt = 0; rt < 2; rt++)
                    acc[rt][ct] = __builtin_amdgcn_mfma_f32_16x16x32_bf16(af[rt][ks], bf, acc[rt][ct], 0, 0, 0);
            }
        }
        int c0 = c0beg + t * 64;
        if (c0 < Mx) {  // fp8-byte feature output
#pragma unroll
            for (int rt = 0; rt < 2; rt++)
#pragma unroll
                for (int r = 0; r < 4; r++) {
                    int gr = gr0 + rt * 16 + r;
                    if (gr >= n) continue;
#pragma unroll
                    for (int ct = 0; ct < 4; ct++) {
                        float v = acc[rt][ct][r];
                        int p = __builtin_amdgcn_cvt_pk_fp8_f32(v, v, 0, false);
                        x8[(size_t)gr * ldx + c0 + ct * 16 + colBase] = (unsigned char)(p & 0xff);
                    }
                }
        } else {
#pragma unroll
            for (int rt = 0; rt < 2; rt++)
#pragma unroll
                for (int r = 0; r < 4; r++) {
                    int gr = gr0 + rt * 16 + r;
                    if (gr >= n) continue;
#pragma unroll
                    for (int ct = 0; ct < 4; ct++) {
                        int c2 = c0 + ct * 16 + colBase - Mx;
                        float v = acc[rt][ct][r] + bias1[c2];
                        if (bias2) v += bias2[c2];
                        if (LINBF) linb[(size_t)gr * ldl + c2] = (__bf16)v;
                        else       linf[(size_t)gr * ldl + c2] = v;
                    }
                }
        }
    }
    if (blockIdx.y == 1) {  // attn mini-tile: 4 a_s + 4 a_d cols (L2-hot)
        floatx4 acc2[2] = {};
        const __bf16* bp = Bt + (size_t)(Mtot + colBase) * K + kOff;
#pragma unroll
        for (int ks = 0; ks < KS; ks++) {
            bf16x8 bf = *(const bf16x8*)(bp + ks * 32);
#pragma unroll
            for (int rt = 0; rt < 2; rt++)
                acc2[rt] = __builtin_amdgcn_mfma_f32_16x16x32_bf16(af[rt][ks], bf, acc2[rt], 0, 0, 0);
        }
        if (colBase < 8) {
            float* dst = (colBase < 4) ? a_s : a_d;
            int h = colBase & 3;
#pragma unroll
            for (int rt = 0; rt < 2; rt++)
#pragma unroll
                for (int r = 0; r < 4; r++) {
                    int gr = gr0 + rt * 16 + r;
                    if (gr < n) dst[gr * 4 + h] = acc2[rt][r];
                }
        }
    }
}

// ---- combined-CSR build (side-1 ids offset by n) ----
__global__ void k_hist2(const int* __restrict__ el, const int* __restrict__ er,
                        int E, int n, int* __restrict__ deg) {
    int e = blockIdx.x * blockDim.x + threadIdx.x;
    if (e >= 2 * E) return;
    int d = (e < E) ? el[E + e] : er[E + (e - E)] + n;
    atomicAdd(&deg[d], 1);
}

__global__ __launch_bounds__(1024) void k_scan(int* __restrict__ rp, int n) {
    __shared__ int wsum[16];
    __shared__ int s_carry;
    int lane = threadIdx.x & 63, wid = threadIdx.x >> 6;
    if (threadIdx.x == 0) s_carry = 0;
    __syncthreads();
    for (int base = 0; base < n; base += 1024) {
        int i = base + threadIdx.x;
        int v = (i < n) ? rp[i] : 0;
        int inc = v;
#pragma unroll
        for (int off = 1; off < 64; off <<= 1) {
            int t = __shfl_up(inc, off, 64);
            if (lane >= off) inc += t;
        }
        if (lane == 63) wsum[wid] = inc;
        __syncthreads();
        int carry = s_carry;
        __syncthreads();
        if (wid == 0) {
            int wv = (lane < 16) ? wsum[lane] : 0;
            int winc = wv;
#pragma unroll
            for (int off = 1; off < 16; off <<= 1) {
                int t = __shfl_up(winc, off, 64);
                if (lane >= off) winc += t;
            }
            if (lane < 16) wsum[lane] = winc - wv;
            if (lane == 15) s_carry = carry + winc;
        }
        __syncthreads();
        if (i < n) rp[i] = carry + wsum[wid] + (inc - v);
        __syncthreads();
    }
}

__global__ void k_fill2(const int* __restrict__ el, const int* __restrict__ er,
                        int E, int n, int* __restrict__ rp, int* __restrict__ csr) {
    int e = blockIdx.x * blockDim.x + threadIdx.x;
    if (e >= 2 * E) return;
    int d, s;
    if (e < E) { s = el[e]; d = el[E + e]; }
    else       { s = er[e - E] + n; d = er[E + (e - E)] + n; }
    int pos = atomicAdd(&rp[d], 1);
    csr[pos] = s;
}

__device__ __forceinline__ void dec4(unsigned int u, float* f) {
    f32x2 a = __builtin_amdgcn_cvt_pk_f32_fp8(u, false);
    f32x2 b = __builtin_amdgcn_cvt_pk_f32_fp8(u, true);
    f[0] = a[0]; f[1] = a[1]; f[2] = b[0]; f[3] = b[1];
}

// Layers 1/2 aggregation, 1 node/wave: 64 lanes x 4 fp8 ch each, depth-3 prefetch.
// out_bf = bf16(relu(agg/z + lin)); lin is bf16.
__global__ __launch_bounds__(256) void k_agg12(const int* __restrict__ rp,
                                               const int* __restrict__ csr,
                                               const float* __restrict__ a_s,
                                               const float* __restrict__ a_d,
                                               const unsigned char* __restrict__ x8,
                                               const __bf16* __restrict__ lin,
                                               __bf16* __restrict__ out_bf, int n) {
    int node = (int)((blockIdx.x * blockDim.x + threadIdx.x) >> 6);
    if (node >= n) return;
    int lane = threadIdx.x & 63;
    int c0 = lane * 4;     // 4 fp8 ch per lane
    int h = lane >> 4;
    int start = node ? rp[node - 1] : 0;
    int end = rp[node];
    float ad = a_d[node * 4 + h];
    float z = __expf(lrelu(a_s[node * 4 + h] + ad));
    float acc[4];
    {
        unsigned int u = *(const unsigned int*)(x8 + (size_t)node * 256 + c0);
        float f[4];
        dec4(u, f);
#pragma unroll
        for (int j = 0; j < 4; j++) acc[j] = z * f[j];
    }
    unsigned int u0 = 0, u1 = 0, u2 = 0;
    float A0 = 0.f, A1 = 0.f, A2 = 0.f;
    if (start < end) {
        int s = csr[start];
        u0 = *(const unsigned int*)(x8 + (size_t)s * 256 + c0);
        A0 = a_s[s * 4 + h];
    }
    if (start + 1 < end) {
        int s = csr[start + 1];
        u1 = *(const unsigned int*)(x8 + (size_t)s * 256 + c0);
        A1 = a_s[s * 4 + h];
    }
    if (start + 2 < end) {
        int s = csr[start + 2];
        u2 = *(const unsigned int*)(x8 + (size_t)s * 256 + c0);
        A2 = a_s[s * 4 + h];
    }
    for (int e = start; e < end; e++) {
        unsigned int uc = u0;
        float ac = A0;
        u0 = u1; A0 = A1;
        u1 = u2; A1 = A2;
        if (e + 3 < end) {
            int s = csr[e + 3];
            u2 = *(const unsigned int*)(x8 + (size_t)s * 256 + c0);
            A2 = a_s[s * 4 + h];
        }
        float w = __expf(lrelu(ac + ad));
        z += w;
        float f[4];
        dec4(uc, f);
#pragma unroll
        for (int q = 0; q < 4; q++) acc[q] += w * f[q];
    }
    float inv = 1.f / (z + 1e-16f);
    bf16x4 l = *(const bf16x4*)(lin + (size_t)node * 256 + c0);
    bf16x4 r;
#pragma unroll
    for (int j = 0; j < 4; j++)
        r[j] = (__bf16)fmaxf(acc[j] * inv + (float)l[j], 0.f);
    *(bf16x4*)(out_bf + (size_t)node * 256 + c0) = r;
}

// Layer-3 aggregation (HC=512), 1 node/wave: 64 lanes x 8 fp8 ch, depth-3 prefetch;
// per-head alpha-normalize then cross-head butterfly mean -> mean[n,128]
__global__ __launch_bounds__(256) void k_agg3(const int* __restrict__ rp,
                                              const int* __restrict__ csr,
                                              const float* __restrict__ a_s,
                                              const float* __restrict__ a_d,
                                              const unsigned char* __restrict__ x8,
                                              float* __restrict__ mean, int n) {
    int node = (int)((blockIdx.x * blockDim.x + threadIdx.x) >> 6);
    if (node >= n) return;
    int lane = threadIdx.x & 63;
    int c0 = lane * 8;     // 8 fp8 ch per lane (global ch in [0,512))
    int h = lane >> 4;
    int start = node ? rp[node - 1] : 0;
    int end = rp[node];
    float ad = a_d[node * 4 + h];
    float z = __expf(lrelu(a_s[node * 4 + h] + ad));
    float acc[8];
    {
        uint2 u = *(const uint2*)(x8 + (size_t)node * 512 + c0);
        float f[8];
        dec4(u.x, f); dec4(u.y, f + 4);
#pragma unroll
        for (int j = 0; j < 8; j++) acc[j] = z * f[j];
    }
    uint2 u0 = {}, u1 = {}, u2 = {};
    float A0 = 0.f, A1 = 0.f, A2 = 0.f;
    if (start < end) {
        int s = csr[start];
        u0 = *(const uint2*)(x8 + (size_t)s * 512 + c0);
        A0 = a_s[s * 4 + h];
    }
    if (start + 1 < end) {
        int s = csr[start + 1];
        u1 = *(const uint2*)(x8 + (size_t)s * 512 + c0);
        A1 = a_s[s * 4 + h];
    }
    if (start + 2 < end) {
        int s = csr[start + 2];
        u2 = *(const uint2*)(x8 + (size_t)s * 512 + c0);
        A2 = a_s[s * 4 + h];
    }
    for (int e = start; e < end; e++) {
        uint2 uc = u0;
        float ac = A0;
        u0 = u1; A0 = A1;
        u1 = u2; A1 = A2;
        if (e + 3 < end) {
            int s = csr[e + 3];
            u2 = *(const uint2*)(x8 + (size_t)s * 512 + c0);
            A2 = a_s[s * 4 + h];
        }
        float w = __expf(lrelu(ac + ad));
        z += w;
        float f[8];
        dec4(uc.x, f); dec4(uc.y, f + 4);
#pragma unroll
        for (int q = 0; q < 8; q++) acc[q] += w * f[q];
    }
    float scale = 0.25f / (z + 1e-16f);  // per-head normalize + /4 head-mean
#pragma unroll
    for (int j = 0; j < 8; j++) {
        float v = acc[j] * scale;
        v += __shfl_xor(v, 16, 64);      // combine head bit 0
        v += __shfl_xor(v, 32, 64);      // combine head bit 1
        acc[j] = v;
    }
    if (lane < 16) {  // lanes 0..15 hold channels lane*8..lane*8+7
        float4* op = (float4*)(mean + (size_t)node * 128 + lane * 8);
        float4 o0 = {acc[0], acc[1], acc[2], acc[3]};
        float4 o1 = {acc[4], acc[5], acc[6], acc[7]};
        op[0] = o0; op[1] = o1;
    }
}

// per-graph mean pool (2G blocks), inline binary search on sorted batch
__global__ __launch_bounds__(128) void k_pool(const float* __restrict__ mean,
                                              const float* __restrict__ lin3,
                                              const float* __restrict__ b3,
                                              const int* __restrict__ bl,
                                              const int* __restrict__ br,
                                              int n, float* __restrict__ out) {
    int g = blockIdx.x, c = threadIdx.x;
    const int* b = (g < GG) ? bl : br;
    int tg = (g < GG) ? g : g - GG;
    int off = (g < GG) ? 0 : n;
    int s, e;
    { int lo = 0, hi = n; while (lo < hi) { int m = (lo + hi) >> 1; if (b[m] < tg) lo = m + 1; else hi = m; } s = lo; }
    { int lo = 0, hi = n; while (lo < hi) { int m = (lo + hi) >> 1; if (b[m] < tg + 1) lo = m + 1; else hi = m; } e = lo; }
    s += off; e += off;
    float acc = 0.f;
    for (int i = s; i < e; i++)
        acc += mean[(size_t)i * 128 + c] + lin3[(size_t)i * 128 + c];
    int cnt = e - s;
    out[(size_t)g * 128 + c] = cnt > 0 ? acc / (float)cnt + b3[c] : 0.f;
}

static inline int cdiv(int a, int b) { return (a + b - 1) / b; }

extern "C" void kernel_launch(void* const* d_in, const int* in_sizes, int n_in,
                              void* d_out, int out_size, void* d_ws, size_t ws_size,
                              hipStream_t stream) {
    const int* x_l = (const int*)d_in[0];
    const int* edge_l = (const int*)d_in[1];
    const int* batch_l = (const int*)d_in[2];
    const int* x_r = (const int*)d_in[3];
    const int* edge_r = (const int*)d_in[4];
    const int* batch_r = (const int*)d_in[5];
    const float* emb = (const float*)d_in[6];
    const float* W1 = (const float*)d_in[7];
    const float* as1 = (const float*)d_in[8];
    const float* ad1 = (const float*)d_in[9];
    const float* b1 = (const float*)d_in[10];
    const float* lw1 = (const float*)d_in[11];
    const float* lb1 = (const float*)d_in[12];
    const float* W2 = (const float*)d_in[13];
    const float* as2 = (const float*)d_in[14];
    const float* ad2 = (const float*)d_in[15];
    const float* b2 = (const float*)d_in[16];
    const float* lw2 = (const float*)d_in[17];
    const float* lb2 = (const float*)d_in[18];
    const float* W3 = (const float*)d_in[19];
    const float* as3 = (const float*)d_in[20];
    const float* ad3 = (const float*)d_in[21];
    const float* b3 = (const float*)d_in[22];
    const float* lw3 = (const float*)d_in[23];
    const float* lb3 = (const float*)d_in[24];

    const int n = in_sizes[0];       // 20000
    const int E = in_sizes[1] / 2;   // 320000
    const int N2 = 2 * n;

    float* MEAN = (float*)d_ws;                // [N2,128]
    float* L3 = MEAN + (size_t)N2 * 128;       // [N2,128] fp32 layer-3 skip
    float* a_s = L3 + (size_t)N2 * 128;        // [N2,4]
    float* a_d = a_s + (size_t)N2 * 4;
    int* rp = (int*)(a_d + (size_t)N2 * 4);    // [N2]
    int* csr = rp + N2;                        // [2E]
    __bf16* LINb = (__bf16*)(csr + 2 * E);     // [N2,256] bf16 skip (layers 1/2)
    unsigned char* X8a = (unsigned char*)(LINb + (size_t)N2 * 256);  // [N2,256] fp8
    unsigned char* X8b = X8a + (size_t)N2 * 256;                     // [N2,512] fp8
    __bf16* Abf = (__bf16*)(X8b + (size_t)N2 * 512);                 // [N2,256] GEMM A
    __bf16* B1t = Abf + (size_t)N2 * 256;  // 528 x 128
    __bf16* B2t = B1t + 528 * 128;         // 528 x 256
    __bf16* B3t = B2t + 528 * 256;         // 656 x 256

    const int TB = 256;
    dim3 blk(TB);

    // fused weight prep (1 dispatch)
    k_wprep<<<cdiv(370688, TB), blk, 0, stream>>>(W1, lw1, as1, ad1, W2, lw2, as2, ad2,
                                                  W3, lw3, as3, ad3, B1t, B2t, B3t);

    // combined CSR (once for all 3 layers, both sides)
    hipMemsetAsync(rp, 0, sizeof(int) * (size_t)N2, stream);
    k_hist2<<<cdiv(2 * E, TB), blk, 0, stream>>>(edge_l, edge_r, E, n, rp);
    k_scan<<<1, 1024, 0, stream>>>(rp, N2);
    k_fill2<<<cdiv(2 * E, TB), blk, 0, stream>>>(edge_l, edge_r, E, n, rp, csr);

    // ---- layer 1 (K=128, embed fused, Mx=256 -> fp8, Ml=256 -> bf16 lin) ----
    k_gemm_all<128, true, true><<<dim3(cdiv(N2, 128), 2), blk, 0, stream>>>(
        nullptr, x_l, x_r, emb, B1t, N2, n, 256, 256, X8a, 256, nullptr, LINb, 256, lb1, b1, a_s, a_d);
    k_agg12<<<cdiv(N2 * 64, TB), blk, 0, stream>>>(rp, csr, a_s, a_d, X8a, LINb, Abf, N2);

    // ---- layer 2 (K=256, Mx=256 -> fp8, Ml=256 -> bf16 lin) ----
    k_gemm_all<256, false, true><<<dim3(cdiv(N2, 128), 2), blk, 0, stream>>>(
        Abf, nullptr, nullptr, nullptr, B2t, N2, n, 256, 256, X8a, 256, nullptr, LINb, 256, lb2, b2, a_s, a_d);
    k_agg12<<<cdiv(N2 * 64, TB), blk, 0, stream>>>(rp, csr, a_s, a_d, X8a, LINb, Abf, N2);

    // ---- layer 3 (K=256, Mx=512 -> fp8, Ml=128 -> fp32 L3) ----
    k_gemm_all<256, false, false><<<dim3(cdiv(N2, 128), 2), blk, 0, stream>>>(
        Abf, nullptr, nullptr, nullptr, B3t, N2, n, 512, 128, X8b, 512, L3, nullptr, 128, lb3, nullptr, a_s, a_d);
    k_agg3<<<cdiv(N2 * 64, TB), blk, 0, stream>>>(rp, csr, a_s, a_d, X8b, MEAN, N2);
    k_pool<<<2 * GG, 128, 0, stream>>>(MEAN, L3, b3, batch_l, batch_r, n, (float*)d_out);
}

// Round 12
// 500.878 us; speedup vs baseline: 1.1755x; 1.1755x over previous
//
#include <hip/hip_runtime.h>

#define GG 256

typedef __bf16 bf16x8 __attribute__((ext_vector_type(8)));
typedef float floatx4 __attribute__((ext_vector_type(4)));
typedef float f32x2 __attribute__((ext_vector_type(2)));

__device__ __forceinline__ float lrelu(float x) { return x > 0.f ? x : 0.2f * x; }

// ---- fused weight prep ----
__device__ __forceinline__ void wt1(const float* __restrict__ B, __bf16* __restrict__ Bt,
                                    int K, int M, int idx) {
    int k = idx / M, m = idx - k * M;
    Bt[(size_t)m * K + k] = (__bf16)B[idx];
}
__device__ __forceinline__ void wattn1(const float* __restrict__ W,
                                       const float* __restrict__ as_,
                                       const float* __restrict__ ad_,
                                       __bf16* __restrict__ dst, int K, int C, int idx) {
    int j = idx / K, k = idx - j * K;
    float v = 0.f;
    if (j < 8) {
        int h = j & 3;
        const float* att = (j < 4) ? as_ : ad_;
        int M = 4 * C;
        for (int c = 0; c < C; c++) v += W[(size_t)k * M + h * C + c] * att[h * C + c];
    }
    dst[(size_t)j * K + k] = (__bf16)v;
}

__global__ void k_wprep(const float* W1, const float* lw1, const float* as1, const float* ad1,
                        const float* W2, const float* lw2, const float* as2, const float* ad2,
                        const float* W3, const float* lw3, const float* as3, const float* ad3,
                        __bf16* B1t, __bf16* B2t, __bf16* B3t) {
    int idx = blockIdx.x * blockDim.x + threadIdx.x;
    if (idx < 32768) { wt1(W1, B1t, 128, 256, idx); return; }
    idx -= 32768;
    if (idx < 32768) { wt1(lw1, B1t + 256 * 128, 128, 256, idx); return; }
    idx -= 32768;
    if (idx < 2048) { wattn1(W1, as1, ad1, B1t + 512 * 128, 128, 64, idx); return; }
    idx -= 2048;
    if (idx < 65536) { wt1(W2, B2t, 256, 256, idx); return; }
    idx -= 65536;
    if (idx < 65536) { wt1(lw2, B2t + 256 * 256, 256, 256, idx); return; }
    idx -= 65536;
    if (idx < 4096) { wattn1(W2, as2, ad2, B2t + 512 * 256, 256, 64, idx); return; }
    idx -= 4096;
    if (idx < 131072) { wt1(W3, B3t, 256, 512, idx); return; }
    idx -= 131072;
    if (idx < 32768) { wt1(lw3, B3t + 512 * 256, 256, 128, idx); return; }
    idx -= 32768;
    if (idx < 4096) { wattn1(W3, as3, ad3, B3t + 640 * 256, 256, 128, idx); return; }
}

// All-in-one GEMM (round-10 64-row structure), register-pipelined B staging.
// cols<Mx -> fp8 bytes; [Mx,Mtot) -> lin (LINBF ? bf16 : fp32) +bias1(+bias2);
// mini-tile [Mtot,Mtot+16) -> a_s/a_d (blockIdx.y==1 only).
template <int K, bool EMB, bool LINBF>
__global__ __launch_bounds__(256) void k_gemm_all(const __bf16* __restrict__ A,
                                                  const int* __restrict__ xl,
                                                  const int* __restrict__ xr,
                                                  const float* __restrict__ emb,
                                                  const __bf16* __restrict__ Bt,
                                                  int n, int n1, int Mx, int Ml,
                                                  unsigned char* __restrict__ x8, int ldx,
                                                  float* __restrict__ linf,
                                                  __bf16* __restrict__ linb, int ldl,
                                                  const float* __restrict__ bias1,
                                                  const float* __restrict__ bias2,
                                                  float* __restrict__ a_s,
                                                  float* __restrict__ a_d) {
    constexpr int KS = K / 32;
    constexpr int LDK = K + 8;
    constexpr int LPR = K / 8;
    constexpr int NCH = 64 * LPR / 256;
    __shared__ __bf16 S[64 * LDK];
    int tid = threadIdx.x;
    int wave = tid >> 6, lane = tid & 63;
    int row0 = blockIdx.x * 64;
#pragma unroll
    for (int c = 0; c < NCH; c++) {
        int i = tid + c * 256;
        int r = i / LPR, ko = (i - r * LPR) * 8;
        int gr = row0 + r;
        bf16x8 v = {};
        if (gr < n) {
            if (EMB) {
                int xi = (gr < n1) ? xl[gr] : xr[gr - n1];
                const float4* src = (const float4*)(emb + ((size_t)xi << 7) + ko);
                float4 q0 = src[0], q1 = src[1];
                v = bf16x8{(__bf16)q0.x, (__bf16)q0.y, (__bf16)q0.z, (__bf16)q0.w,
                           (__bf16)q1.x, (__bf16)q1.y, (__bf16)q1.z, (__bf16)q1.w};
            } else {
                v = *(const bf16x8*)(A + (size_t)gr * K + ko);
            }
        }
        *(bf16x8*)&S[r * LDK + ko] = v;
    }
    __syncthreads();
    int kOff = (lane >> 4) * 8;
    int colBase = lane & 15;
    bf16x8 af[KS];
#pragma unroll
    for (int ks = 0; ks < KS; ks++)
        af[ks] = *(const bf16x8*)&S[(wave * 16 + colBase) * LDK + ks * 32 + kOff];
    int Mtot = Mx + Ml;
    int gr0 = row0 + wave * 16 + ((lane >> 4) << 2);
    int half = (Mtot / 128) * 64;
    int c0beg = blockIdx.y * half;
    int T = half / 64;
    bf16x8 regs[NCH];
#pragma unroll
    for (int c = 0; c < NCH; c++) {
        int i = tid + c * 256;
        int r = i / LPR, ko = (i - r * LPR) * 8;
        regs[c] = *(const bf16x8*)(Bt + (size_t)(c0beg + r) * K + ko);
    }
    for (int t = 0; t < T; t++) {
        __syncthreads();
#pragma unroll
        for (int c = 0; c < NCH; c++) {
            int i = tid + c * 256;
            int r = i / LPR, ko = (i - r * LPR) * 8;
            *(bf16x8*)&S[r * LDK + ko] = regs[c];
        }
        if (t + 1 < T) {
            int c0n = c0beg + (t + 1) * 64;
#pragma unroll
            for (int c = 0; c < NCH; c++) {
                int i = tid + c * 256;
                int r = i / LPR, ko = (i - r * LPR) * 8;
                regs[c] = *(const bf16x8*)(Bt + (size_t)(c0n + r) * K + ko);
            }
        }
        __syncthreads();
        floatx4 acc[4] = {};
#pragma unroll
        for (int ct = 0; ct < 4; ct++) {
#pragma unroll
            for (int ks = 0; ks < KS; ks++) {
                bf16x8 bf = *(const bf16x8*)&S[(ct * 16 + colBase) * LDK + ks * 32 + kOff];
                acc[ct] = __builtin_amdgcn_mfma_f32_16x16x32_bf16(af[ks], bf, acc[ct], 0, 0, 0);
            }
        }
        int c0 = c0beg + t * 64;
        if (c0 < Mx) {
#pragma unroll
            for (int r = 0; r < 4; r++) {
                int gr = gr0 + r;
                if (gr >= n) continue;
#pragma unroll
                for (int ct = 0; ct < 4; ct++) {
                    float v = acc[ct][r];
                    int p = __builtin_amdgcn_cvt_pk_fp8_f32(v, v, 0, false);
                    x8[(size_t)gr * ldx + c0 + ct * 16 + colBase] = (unsigned char)(p & 0xff);
                }
            }
        } else {
#pragma unroll
            for (int r = 0; r < 4; r++) {
                int gr = gr0 + r;
                if (gr >= n) continue;
#pragma unroll
                for (int ct = 0; ct < 4; ct++) {
                    int c2 = c0 + ct * 16 + colBase - Mx;
                    float v = acc[ct][r] + bias1[c2];
                    if (bias2) v += bias2[c2];
                    if (LINBF) linb[(size_t)gr * ldl + c2] = (__bf16)v;
                    else       linf[(size_t)gr * ldl + c2] = v;
                }
            }
        }
    }
    if (blockIdx.y == 1) {
        floatx4 acc = {};
        const __bf16* bp = Bt + (size_t)(Mtot + colBase) * K + kOff;
#pragma unroll
        for (int ks = 0; ks < KS; ks++) {
            bf16x8 bf = *(const bf16x8*)(bp + ks * 32);
            acc = __builtin_amdgcn_mfma_f32_16x16x32_bf16(af[ks], bf, acc, 0, 0, 0);
        }
        if (colBase < 8) {
            float* dst = (colBase < 4) ? a_s : a_d;
            int h = colBase & 3;
#pragma unroll
            for (int r = 0; r < 4; r++) {
                int gr = gr0 + r;
                if (gr < n) dst[gr * 4 + h] = acc[r];
            }
        }
    }
}

// ---- combined-CSR build (side-1 ids offset by n) ----
__global__ void k_hist2(const int* __restrict__ el, const int* __restrict__ er,
                        int E, int n, int* __restrict__ deg) {
    int e = blockIdx.x * blockDim.x + threadIdx.x;
    if (e >= 2 * E) return;
    int d = (e < E) ? el[E + e] : er[E + (e - E)] + n;
    atomicAdd(&deg[d], 1);
}

__global__ __launch_bounds__(1024) void k_scan(int* __restrict__ rp, int n) {
    __shared__ int wsum[16];
    __shared__ int s_carry;
    int lane = threadIdx.x & 63, wid = threadIdx.x >> 6;
    if (threadIdx.x == 0) s_carry = 0;
    __syncthreads();
    for (int base = 0; base < n; base += 1024) {
        int i = base + threadIdx.x;
        int v = (i < n) ? rp[i] : 0;
        int inc = v;
#pragma unroll
        for (int off = 1; off < 64; off <<= 1) {
            int t = __shfl_up(inc, off, 64);
            if (lane >= off) inc += t;
        }
        if (lane == 63) wsum[wid] = inc;
        __syncthreads();
        int carry = s_carry;
        __syncthreads();
        if (wid == 0) {
            int wv = (lane < 16) ? wsum[lane] : 0;
            int winc = wv;
#pragma unroll
            for (int off = 1; off < 16; off <<= 1) {
                int t = __shfl_up(winc, off, 64);
                if (lane >= off) winc += t;
            }
            if (lane < 16) wsum[lane] = winc - wv;
            if (lane == 15) s_carry = carry + winc;
        }
        __syncthreads();
        if (i < n) rp[i] = carry + wsum[wid] + (inc - v);
        __syncthreads();
    }
}

__global__ void k_fill2(const int* __restrict__ el, const int* __restrict__ er,
                        int E, int n, int* __restrict__ rp, int* __restrict__ csr) {
    int e = blockIdx.x * blockDim.x + threadIdx.x;
    if (e >= 2 * E) return;
    int d, s;
    if (e < E) { s = el[e]; d = el[E + e]; }
    else       { s = er[e - E] + n; d = er[E + (e - E)] + n; }
    int pos = atomicAdd(&rp[d], 1);
    csr[pos] = s;
}

__device__ __forceinline__ void dec4(unsigned int u, float* f) {
    f32x2 a = __builtin_amdgcn_cvt_pk_f32_fp8(u, false);
    f32x2 b = __builtin_amdgcn_cvt_pk_f32_fp8(u, true);
    f[0] = a[0]; f[1] = a[1]; f[2] = b[0]; f[3] = b[1];
}

// Layers 1/2 aggregation on fp8 rows (256 B): 2 nodes/wave, broadcast csr reads,
// depth-3 prefetch. out_bf = bf16(relu(agg/z + lin)); lin is bf16.
__global__ __launch_bounds__(256) void k_agg12(const int* __restrict__ rp,
                                               const int* __restrict__ csr,
                                               const float* __restrict__ a_s,
                                               const float* __restrict__ a_d,
                                               const unsigned char* __restrict__ x8,
                                               const __bf16* __restrict__ lin,
                                               __bf16* __restrict__ out_bf, int n) {
    int wv = (int)((blockIdx.x * blockDim.x + threadIdx.x) >> 6);
    int lane = threadIdx.x & 63;
    int sub = lane >> 5, sl = lane & 31;
    int node = wv * 2 + sub;
    if (node >= n) return;
    int c0 = sl * 8;
    int h = sl >> 3;
    int start = node ? rp[node - 1] : 0;
    int end = rp[node];
    float ad = a_d[node * 4 + h];
    float z = __expf(lrelu(a_s[node * 4 + h] + ad));
    float acc[8];
    {
        uint2 u = *(const uint2*)(x8 + (size_t)node * 256 + c0);
        float f[8];
        dec4(u.x, f); dec4(u.y, f + 4);
#pragma unroll
        for (int j = 0; j < 8; j++) acc[j] = z * f[j];
    }
    uint2 u0 = {}, u1 = {}, u2 = {};
    float A0 = 0.f, A1 = 0.f, A2 = 0.f;
    if (start < end) {
        int s = csr[start];
        u0 = *(const uint2*)(x8 + (size_t)s * 256 + c0);
        A0 = a_s[s * 4 + h];
    }
    if (start + 1 < end) {
        int s = csr[start + 1];
        u1 = *(const uint2*)(x8 + (size_t)s * 256 + c0);
        A1 = a_s[s * 4 + h];
    }
    if (start + 2 < end) {
        int s = csr[start + 2];
        u2 = *(const uint2*)(x8 + (size_t)s * 256 + c0);
        A2 = a_s[s * 4 + h];
    }
    for (int e = start; e < end; e++) {
        uint2 uc = u0;
        float ac = A0;
        u0 = u1; A0 = A1;
        u1 = u2; A1 = A2;
        if (e + 3 < end) {
            int s = csr[e + 3];
            u2 = *(const uint2*)(x8 + (size_t)s * 256 + c0);
            A2 = a_s[s * 4 + h];
        }
        float w = __expf(lrelu(ac + ad));
        z += w;
        float f[8];
        dec4(uc.x, f); dec4(uc.y, f + 4);
#pragma unroll
        for (int q = 0; q < 8; q++) acc[q] += w * f[q];
    }
    float inv = 1.f / (z + 1e-16f);
    bf16x8 l = *(const bf16x8*)(lin + (size_t)node * 256 + c0);
    bf16x8 r;
#pragma unroll
    for (int j = 0; j < 8; j++)
        r[j] = (__bf16)fmaxf(acc[j] * inv + (float)l[j], 0.f);
    *(bf16x8*)(out_bf + (size_t)node * 256 + c0) = r;
}

// Layer-3 aggregation (HC=512) on fp8 rows; 2 nodes/wave; depth-3 prefetch;
// head-mean via shfl -> mean[n,128]
__global__ __launch_bounds__(256) void k_agg3(const int* __restrict__ rp,
                                              const int* __restrict__ csr,
                                              const float* __restrict__ a_s,
                                              const float* __restrict__ a_d,
                                              const unsigned int* __restrict__ x8,
                                              float* __restrict__ mean, int n) {
    int wv = (int)((blockIdx.x * blockDim.x + threadIdx.x) >> 6);
    int lane = threadIdx.x & 63;
    int sub = lane >> 5, sl = lane & 31;
    int node = wv * 2 + sub;
    if (node >= n) return;
    int h = sl >> 3;
    int start = node ? rp[node - 1] : 0;
    int end = rp[node];
    float ad = a_d[node * 4 + h];
    float z = __expf(lrelu(a_s[node * 4 + h] + ad));
    float acc[16];
    {
        uint4 u = *(const uint4*)(x8 + (size_t)node * 128 + sl * 4);
        float f[16];
        dec4(u.x, f); dec4(u.y, f + 4); dec4(u.z, f + 8); dec4(u.w, f + 12);
#pragma unroll
        for (int j = 0; j < 16; j++) acc[j] = z * f[j];
    }
    uint4 u0 = {}, u1 = {}, u2 = {};
    float A0 = 0.f, A1 = 0.f, A2 = 0.f;
    if (start < end) {
        int s = csr[start];
        u0 = *(const uint4*)(x8 + (size_t)s * 128 + sl * 4);
        A0 = a_s[s * 4 + h];
    }
    if (start + 1 < end) {
        int s = csr[start + 1];
        u1 = *(const uint4*)(x8 + (size_t)s * 128 + sl * 4);
        A1 = a_s[s * 4 + h];
    }
    if (start + 2 < end) {
        int s = csr[start + 2];
        u2 = *(const uint4*)(x8 + (size_t)s * 128 + sl * 4);
        A2 = a_s[s * 4 + h];
    }
    for (int e = start; e < end; e++) {
        uint4 uc = u0;
        float ac = A0;
        u0 = u1; A0 = A1;
        u1 = u2; A1 = A2;
        if (e + 3 < end) {
            int s = csr[e + 3];
            u2 = *(const uint4*)(x8 + (size_t)s * 128 + sl * 4);
            A2 = a_s[s * 4 + h];
        }
        float w = __expf(lrelu(ac + ad));
        z += w;
        float f[16];
        dec4(uc.x, f); dec4(uc.y, f + 4); dec4(uc.z, f + 8); dec4(uc.w, f + 12);
#pragma unroll
        for (int q = 0; q < 16; q++) acc[q] += w * f[q];
    }
    float scale = 0.25f / (z + 1e-16f);
#pragma unroll
    for (int j = 0; j < 16; j++) {
        float v = acc[j] * scale;
        v += __shfl_xor(v, 8, 64);
        v += __shfl_xor(v, 16, 64);
        acc[j] = v;
    }
    if ((sl & 24) == 0) {
        float4* op = (float4*)(mean + (size_t)node * 128 + sl * 16);
#pragma unroll
        for (int q = 0; q < 4; q++) {
            float4 o = {acc[4 * q], acc[4 * q + 1], acc[4 * q + 2], acc[4 * q + 3]};
            op[q] = o;
        }
    }
}

// per-graph mean pool (2G blocks), inline binary search on sorted batch
__global__ __launch_bounds__(128) void k_pool(const float* __restrict__ mean,
                                              const float* __restrict__ lin3,
                                              const float* __restrict__ b3,
                                              const int* __restrict__ bl,
                                              const int* __restrict__ br,
                                              int n, float* __restrict__ out) {
    int g = blockIdx.x, c = threadIdx.x;
    const int* b = (g < GG) ? bl : br;
    int tg = (g < GG) ? g : g - GG;
    int off = (g < GG) ? 0 : n;
    int s, e;
    { int lo = 0, hi = n; while (lo < hi) { int m = (lo + hi) >> 1; if (b[m] < tg) lo = m + 1; else hi = m; } s = lo; }
    { int lo = 0, hi = n; while (lo < hi) { int m = (lo + hi) >> 1; if (b[m] < tg + 1) lo = m + 1; else hi = m; } e = lo; }
    s += off; e += off;
    float acc = 0.f;
    for (int i = s; i < e; i++)
        acc += mean[(size_t)i * 128 + c] + lin3[(size_t)i * 128 + c];
    int cnt = e - s;
    out[(size_t)g * 128 + c] = cnt > 0 ? acc / (float)cnt + b3[c] : 0.f;
}

static inline int cdiv(int a, int b) { return (a + b - 1) / b; }

extern "C" void kernel_launch(void* const* d_in, const int* in_sizes, int n_in,
                              void* d_out, int out_size, void* d_ws, size_t ws_size,
                              hipStream_t stream) {
    const int* x_l = (const int*)d_in[0];
    const int* edge_l = (const int*)d_in[1];
    const int* batch_l = (const int*)d_in[2];
    const int* x_r = (const int*)d_in[3];
    const int* edge_r = (const int*)d_in[4];
    const int* batch_r = (const int*)d_in[5];
    const float* emb = (const float*)d_in[6];
    const float* W1 = (const float*)d_in[7];
    const float* as1 = (const float*)d_in[8];
    const float* ad1 = (const float*)d_in[9];
    const float* b1 = (const float*)d_in[10];
    const float* lw1 = (const float*)d_in[11];
    const float* lb1 = (const float*)d_in[12];
    const float* W2 = (const float*)d_in[13];
    const float* as2 = (const float*)d_in[14];
    const float* ad2 = (const float*)d_in[15];
    const float* b2 = (const float*)d_in[16];
    const float* lw2 = (const float*)d_in[17];
    const float* lb2 = (const float*)d_in[18];
    const float* W3 = (const float*)d_in[19];
    const float* as3 = (const float*)d_in[20];
    const float* ad3 = (const float*)d_in[21];
    const float* b3 = (const float*)d_in[22];
    const float* lw3 = (const float*)d_in[23];
    const float* lb3 = (const float*)d_in[24];

    const int n = in_sizes[0];       // 20000
    const int E = in_sizes[1] / 2;   // 320000
    const int N2 = 2 * n;

    float* MEAN = (float*)d_ws;                // [N2,128]
    float* L3 = MEAN + (size_t)N2 * 128;       // [N2,128] fp32 layer-3 skip
    float* a_s = L3 + (size_t)N2 * 128;        // [N2,4]
    float* a_d = a_s + (size_t)N2 * 4;
    int* rp = (int*)(a_d + (size_t)N2 * 4);    // [N2]
    int* csr = rp + N2;                        // [2E]
    __bf16* LINb = (__bf16*)(csr + 2 * E);     // [N2,256] bf16 skip (layers 1/2)
    unsigned char* X8a = (unsigned char*)(LINb + (size_t)N2 * 256);  // [N2,256] fp8
    unsigned char* X8b = X8a + (size_t)N2 * 256;                     // [N2,512] fp8
    __bf16* Abf = (__bf16*)(X8b + (size_t)N2 * 512);                 // [N2,256] GEMM A
    __bf16* B1t = Abf + (size_t)N2 * 256;  // 528 x 128
    __bf16* B2t = B1t + 528 * 128;         // 528 x 256
    __bf16* B3t = B2t + 528 * 256;         // 656 x 256

    const int TB = 256;
    dim3 blk(TB);

    // fused weight prep (1 dispatch)
    k_wprep<<<cdiv(370688, TB), blk, 0, stream>>>(W1, lw1, as1, ad1, W2, lw2, as2, ad2,
                                                  W3, lw3, as3, ad3, B1t, B2t, B3t);

    // combined CSR (once for all 3 layers, both sides)
    hipMemsetAsync(rp, 0, sizeof(int) * (size_t)N2, stream);
    k_hist2<<<cdiv(2 * E, TB), blk, 0, stream>>>(edge_l, edge_r, E, n, rp);
    k_scan<<<1, 1024, 0, stream>>>(rp, N2);
    k_fill2<<<cdiv(2 * E, TB), blk, 0, stream>>>(edge_l, edge_r, E, n, rp, csr);

    // ---- layer 1 (K=128, embed fused, Mx=256 -> fp8, Ml=256 -> bf16 lin) ----
    k_gemm_all<128, true, true><<<dim3(cdiv(N2, 64), 2), blk, 0, stream>>>(
        nullptr, x_l, x_r, emb, B1t, N2, n, 256, 256, X8a, 256, nullptr, LINb, 256, lb1, b1, a_s, a_d);
    k_agg12<<<cdiv(N2, 8), blk, 0, stream>>>(rp, csr, a_s, a_d, X8a, LINb, Abf, N2);

    // ---- layer 2 (K=256, Mx=256 -> fp8, Ml=256 -> bf16 lin) ----
    k_gemm_all<256, false, true><<<dim3(cdiv(N2, 64), 2), blk, 0, stream>>>(
        Abf, nullptr, nullptr, nullptr, B2t, N2, n, 256, 256, X8a, 256, nullptr, LINb, 256, lb2, b2, a_s, a_d);
    k_agg12<<<cdiv(N2, 8), blk, 0, stream>>>(rp, csr, a_s, a_d, X8a, LINb, Abf, N2);

    // ---- layer 3 (K=256, Mx=512 -> fp8, Ml=128 -> fp32 L3) ----
    k_gemm_all<256, false, false><<<dim3(cdiv(N2, 64), 2), blk, 0, stream>>>(
        Abf, nullptr, nullptr, nullptr, B3t, N2, n, 512, 128, X8b, 512, L3, nullptr, 128, lb3, nullptr, a_s, a_d);
    k_agg3<<<cdiv(N2, 8), blk, 0, stream>>>(rp, csr, a_s, a_d, (const unsigned int*)X8b, MEAN, N2);
    k_pool<<<2 * GG, 128, 0, stream>>>(MEAN, L3, b3, batch_l, batch_r, n, (float*)d_out);
}

// Round 13
// 484.309 us; speedup vs baseline: 1.2157x; 1.0342x over previous
//
#include <hip/hip_runtime.h>

#define GG 256

typedef __bf16 bf16x8 __attribute__((ext_vector_type(8)));
typedef __bf16 bf16x4 __attribute__((ext_vector_type(4)));
typedef float floatx4 __attribute__((ext_vector_type(4)));
typedef float f32x2 __attribute__((ext_vector_type(2)));

__device__ __forceinline__ float lrelu(float x) { return x > 0.f ? x : 0.2f * x; }

// column permutation within each 64-col group: compute-order -> consecutive true cols
__device__ __forceinline__ int permM(int m) {
    int g = m >> 6, q = m & 63;
    return (g << 6) | ((q & 3) << 4) | (q >> 2);
}

// ---- fused weight prep (B rows stored permuted; attn mini-tile unpermuted) ----
__device__ __forceinline__ void wt1(const float* __restrict__ B, __bf16* __restrict__ Bt,
                                    int K, int M, int idx) {
    int k = idx / M, m = idx - k * M;
    Bt[(size_t)permM(m) * K + k] = (__bf16)B[idx];
}
__device__ __forceinline__ void wattn1(const float* __restrict__ W,
                                       const float* __restrict__ as_,
                                       const float* __restrict__ ad_,
                                       __bf16* __restrict__ dst, int K, int C, int idx) {
    int j = idx / K, k = idx - j * K;
    float v = 0.f;
    if (j < 8) {
        int h = j & 3;
        const float* att = (j < 4) ? as_ : ad_;
        int M = 4 * C;
        for (int c = 0; c < C; c++) v += W[(size_t)k * M + h * C + c] * att[h * C + c];
    }
    dst[(size_t)j * K + k] = (__bf16)v;
}

__global__ void k_wprep(const float* W1, const float* lw1, const float* as1, const float* ad1,
                        const float* W2, const float* lw2, const float* as2, const float* ad2,
                        const float* W3, const float* lw3, const float* as3, const float* ad3,
                        __bf16* B1t, __bf16* B2t, __bf16* B3t) {
    int idx = blockIdx.x * blockDim.x + threadIdx.x;
    if (idx < 32768) { wt1(W1, B1t, 128, 256, idx); return; }
    idx -= 32768;
    if (idx < 32768) { wt1(lw1, B1t + 256 * 128, 128, 256, idx); return; }
    idx -= 32768;
    if (idx < 2048) { wattn1(W1, as1, ad1, B1t + 512 * 128, 128, 64, idx); return; }
    idx -= 2048;
    if (idx < 65536) { wt1(W2, B2t, 256, 256, idx); return; }
    idx -= 65536;
    if (idx < 65536) { wt1(lw2, B2t + 256 * 256, 256, 256, idx); return; }
    idx -= 65536;
    if (idx < 4096) { wattn1(W2, as2, ad2, B2t + 512 * 256, 256, 64, idx); return; }
    idx -= 4096;
    if (idx < 131072) { wt1(W3, B3t, 256, 512, idx); return; }
    idx -= 131072;
    if (idx < 32768) { wt1(lw3, B3t + 512 * 256, 256, 128, idx); return; }
    idx -= 32768;
    if (idx < 4096) { wattn1(W3, as3, ad3, B3t + 640 * 256, 256, 128, idx); return; }
}

// All-in-one GEMM (64-row blocks, register-pipelined B staging, packed epilogue).
// B cols are storage-permuted so lane's 4 ct outputs = 4 consecutive true cols.
// cols<Mx -> packed fp8 dword; [Mx,Mtot) -> lin (LINBF ? bf16x4 : float4) +bias;
// mini-tile [Mtot,Mtot+16) -> a_s/a_d (blockIdx.y==1 only).
template <int K, bool EMB, bool LINBF>
__global__ __launch_bounds__(256) void k_gemm_all(const __bf16* __restrict__ A,
                                                  const int* __restrict__ xl,
                                                  const int* __restrict__ xr,
                                                  const float* __restrict__ emb,
                                                  const __bf16* __restrict__ Bt,
                                                  int n, int n1, int Mx, int Ml,
                                                  unsigned char* __restrict__ x8, int ldx,
                                                  float* __restrict__ linf,
                                                  __bf16* __restrict__ linb, int ldl,
                                                  const float* __restrict__ bias1,
                                                  const float* __restrict__ bias2,
                                                  float* __restrict__ a_s,
                                                  float* __restrict__ a_d) {
    constexpr int KS = K / 32;
    constexpr int LDK = K + 8;
    constexpr int LPR = K / 8;
    constexpr int NCH = 64 * LPR / 256;
    __shared__ __bf16 S[64 * LDK];
    int tid = threadIdx.x;
    int wave = tid >> 6, lane = tid & 63;
    int row0 = blockIdx.x * 64;
#pragma unroll
    for (int c = 0; c < NCH; c++) {
        int i = tid + c * 256;
        int r = i / LPR, ko = (i - r * LPR) * 8;
        int gr = row0 + r;
        bf16x8 v = {};
        if (gr < n) {
            if (EMB) {
                int xi = (gr < n1) ? xl[gr] : xr[gr - n1];
                const float4* src = (const float4*)(emb + ((size_t)xi << 7) + ko);
                float4 q0 = src[0], q1 = src[1];
                v = bf16x8{(__bf16)q0.x, (__bf16)q0.y, (__bf16)q0.z, (__bf16)q0.w,
                           (__bf16)q1.x, (__bf16)q1.y, (__bf16)q1.z, (__bf16)q1.w};
            } else {
                v = *(const bf16x8*)(A + (size_t)gr * K + ko);
            }
        }
        *(bf16x8*)&S[r * LDK + ko] = v;
    }
    __syncthreads();
    int kOff = (lane >> 4) * 8;
    int colBase = lane & 15;
    bf16x8 af[KS];
#pragma unroll
    for (int ks = 0; ks < KS; ks++)
        af[ks] = *(const bf16x8*)&S[(wave * 16 + colBase) * LDK + ks * 32 + kOff];
    int Mtot = Mx + Ml;
    int gr0 = row0 + wave * 16 + ((lane >> 4) << 2);
    int half = (Mtot / 128) * 64;
    int c0beg = blockIdx.y * half;
    int T = half / 64;
    bf16x8 regs[NCH];
#pragma unroll
    for (int c = 0; c < NCH; c++) {
        int i = tid + c * 256;
        int r = i / LPR, ko = (i - r * LPR) * 8;
        regs[c] = *(const bf16x8*)(Bt + (size_t)(c0beg + r) * K + ko);
    }
    for (int t = 0; t < T; t++) {
        __syncthreads();
#pragma unroll
        for (int c = 0; c < NCH; c++) {
            int i = tid + c * 256;
            int r = i / LPR, ko = (i - r * LPR) * 8;
            *(bf16x8*)&S[r * LDK + ko] = regs[c];
        }
        if (t + 1 < T) {
            int c0n = c0beg + (t + 1) * 64;
#pragma unroll
            for (int c = 0; c < NCH; c++) {
                int i = tid + c * 256;
                int r = i / LPR, ko = (i - r * LPR) * 8;
                regs[c] = *(const bf16x8*)(Bt + (size_t)(c0n + r) * K + ko);
            }
        }
        __syncthreads();
        floatx4 acc[4] = {};
#pragma unroll
        for (int ct = 0; ct < 4; ct++) {
#pragma unroll
            for (int ks = 0; ks < KS; ks++) {
                bf16x8 bf = *(const bf16x8*)&S[(ct * 16 + colBase) * LDK + ks * 32 + kOff];
                acc[ct] = __builtin_amdgcn_mfma_f32_16x16x32_bf16(af[ks], bf, acc[ct], 0, 0, 0);
            }
        }
        int c0 = c0beg + t * 64;
        // lane's 4 ct outputs are true cols c0 + colBase*4 + {0,1,2,3}
        if (c0 < Mx) {  // packed fp8 dword store per row
#pragma unroll
            for (int r = 0; r < 4; r++) {
                int gr = gr0 + r;
                if (gr >= n) continue;
                int p = __builtin_amdgcn_cvt_pk_fp8_f32(acc[0][r], acc[1][r], 0, false);
                p = __builtin_amdgcn_cvt_pk_fp8_f32(acc[2][r], acc[3][r], p, true);
                *(unsigned int*)(x8 + (size_t)gr * ldx + c0 + colBase * 4) = (unsigned int)p;
            }
        } else {
            int c2 = c0 + colBase * 4 - Mx;
#pragma unroll
            for (int r = 0; r < 4; r++) {
                int gr = gr0 + r;
                if (gr >= n) continue;
                float v0 = acc[0][r] + bias1[c2 + 0];
                float v1 = acc[1][r] + bias1[c2 + 1];
                float v2 = acc[2][r] + bias1[c2 + 2];
                float v3 = acc[3][r] + bias1[c2 + 3];
                if (bias2) {
                    v0 += bias2[c2 + 0]; v1 += bias2[c2 + 1];
                    v2 += bias2[c2 + 2]; v3 += bias2[c2 + 3];
                }
                if (LINBF) {
                    bf16x4 o = {(__bf16)v0, (__bf16)v1, (__bf16)v2, (__bf16)v3};
                    *(bf16x4*)(linb + (size_t)gr * ldl + c2) = o;
                } else {
                    float4 o = {v0, v1, v2, v3};
                    *(float4*)(linf + (size_t)gr * ldl + c2) = o;
                }
            }
        }
    }
    if (blockIdx.y == 1) {  // attn mini-tile (unpermuted rows)
        floatx4 acc = {};
        const __bf16* bp = Bt + (size_t)(Mtot + colBase) * K + kOff;
#pragma unroll
        for (int ks = 0; ks < KS; ks++) {
            bf16x8 bf = *(const bf16x8*)(bp + ks * 32);
            acc = __builtin_amdgcn_mfma_f32_16x16x32_bf16(af[ks], bf, acc, 0, 0, 0);
        }
        if (colBase < 8) {
            float* dst = (colBase < 4) ? a_s : a_d;
            int h = colBase & 3;
#pragma unroll
            for (int r = 0; r < 4; r++) {
                int gr = gr0 + r;
                if (gr < n) dst[gr * 4 + h] = acc[r];
            }
        }
    }
}

// ---- combined-CSR build (side-1 ids offset by n) ----
__global__ void k_hist2(const int* __restrict__ el, const int* __restrict__ er,
                        int E, int n, int* __restrict__ deg) {
    int e = blockIdx.x * blockDim.x + threadIdx.x;
    if (e >= 2 * E) return;
    int d = (e < E) ? el[E + e] : er[E + (e - E)] + n;
    atomicAdd(&deg[d], 1);
}

__global__ __launch_bounds__(1024) void k_scan(int* __restrict__ rp, int n) {
    __shared__ int wsum[16];
    __shared__ int s_carry;
    int lane = threadIdx.x & 63, wid = threadIdx.x >> 6;
    if (threadIdx.x == 0) s_carry = 0;
    __syncthreads();
    for (int base = 0; base < n; base += 1024) {
        int i = base + threadIdx.x;
        int v = (i < n) ? rp[i] : 0;
        int inc = v;
#pragma unroll
        for (int off = 1; off < 64; off <<= 1) {
            int t = __shfl_up(inc, off, 64);
            if (lane >= off) inc += t;
        }
        if (lane == 63) wsum[wid] = inc;
        __syncthreads();
        int carry = s_carry;
        __syncthreads();
        if (wid == 0) {
            int wv = (lane < 16) ? wsum[lane] : 0;
            int winc = wv;
#pragma unroll
            for (int off = 1; off < 16; off <<= 1) {
                int t = __shfl_up(winc, off, 64);
                if (lane >= off) winc += t;
            }
            if (lane < 16) wsum[lane] = winc - wv;
            if (lane == 15) s_carry = carry + winc;
        }
        __syncthreads();
        if (i < n) rp[i] = carry + wsum[wid] + (inc - v);
        __syncthreads();
    }
}

__global__ void k_fill2(const int* __restrict__ el, const int* __restrict__ er,
                        int E, int n, int* __restrict__ rp, int* __restrict__ csr) {
    int e = blockIdx.x * blockDim.x + threadIdx.x;
    if (e >= 2 * E) return;
    int d, s;
    if (e < E) { s = el[e]; d = el[E + e]; }
    else       { s = er[e - E] + n; d = er[E + (e - E)] + n; }
    int pos = atomicAdd(&rp[d], 1);
    csr[pos] = s;
}

__device__ __forceinline__ void dec4(unsigned int u, float* f) {
    f32x2 a = __builtin_amdgcn_cvt_pk_f32_fp8(u, false);
    f32x2 b = __builtin_amdgcn_cvt_pk_f32_fp8(u, true);
    f[0] = a[0]; f[1] = a[1]; f[2] = b[0]; f[3] = b[1];
}

// Layers 1/2 aggregation on fp8 rows (256 B): 2 nodes/wave, depth-3 prefetch.
// out_bf = bf16(relu(agg/z + lin)); lin is bf16.
__global__ __launch_bounds__(256) void k_agg12(const int* __restrict__ rp,
                                               const int* __restrict__ csr,
                                               const float* __restrict__ a_s,
                                               const float* __restrict__ a_d,
                                               const unsigned char* __restrict__ x8,
                                               const __bf16* __restrict__ lin,
                                               __bf16* __restrict__ out_bf, int n) {
    int wv = (int)((blockIdx.x * blockDim.x + threadIdx.x) >> 6);
    int lane = threadIdx.x & 63;
    int sub = lane >> 5, sl = lane & 31;
    int node = wv * 2 + sub;
    if (node >= n) return;
    int c0 = sl * 8;
    int h = sl >> 3;
    int start = node ? rp[node - 1] : 0;
    int end = rp[node];
    float ad = a_d[node * 4 + h];
    float z = __expf(lrelu(a_s[node * 4 + h] + ad));
    float acc[8];
    {
        uint2 u = *(const uint2*)(x8 + (size_t)node * 256 + c0);
        float f[8];
        dec4(u.x, f); dec4(u.y, f + 4);
#pragma unroll
        for (int j = 0; j < 8; j++) acc[j] = z * f[j];
    }
    uint2 u0 = {}, u1 = {}, u2 = {};
    float A0 = 0.f, A1 = 0.f, A2 = 0.f;
    if (start < end) {
        int s = csr[start];
        u0 = *(const uint2*)(x8 + (size_t)s * 256 + c0);
        A0 = a_s[s * 4 + h];
    }
    if (start + 1 < end) {
        int s = csr[start + 1];
        u1 = *(const uint2*)(x8 + (size_t)s * 256 + c0);
        A1 = a_s[s * 4 + h];
    }
    if (start + 2 < end) {
        int s = csr[start + 2];
        u2 = *(const uint2*)(x8 + (size_t)s * 256 + c0);
        A2 = a_s[s * 4 + h];
    }
    for (int e = start; e < end; e++) {
        uint2 uc = u0;
        float ac = A0;
        u0 = u1; A0 = A1;
        u1 = u2; A1 = A2;
        if (e + 3 < end) {
            int s = csr[e + 3];
            u2 = *(const uint2*)(x8 + (size_t)s * 256 + c0);
            A2 = a_s[s * 4 + h];
        }
        float w = __expf(lrelu(ac + ad));
        z += w;
        float f[8];
        dec4(uc.x, f); dec4(uc.y, f + 4);
#pragma unroll
        for (int q = 0; q < 8; q++) acc[q] += w * f[q];
    }
    float inv = 1.f / (z + 1e-16f);
    bf16x8 l = *(const bf16x8*)(lin + (size_t)node * 256 + c0);
    bf16x8 r;
#pragma unroll
    for (int j = 0; j < 8; j++)
        r[j] = (__bf16)fmaxf(acc[j] * inv + (float)l[j], 0.f);
    *(bf16x8*)(out_bf + (size_t)node * 256 + c0) = r;
}

// Layer-3 aggregation (HC=512) on fp8 rows; 2 nodes/wave; depth-3 prefetch;
// head-mean via shfl -> mean[n,128]
__global__ __launch_bounds__(256) void k_agg3(const int* __restrict__ rp,
                                              const int* __restrict__ csr,
                                              const float* __restrict__ a_s,
                                              const float* __restrict__ a_d,
                                              const unsigned int* __restrict__ x8,
                                              float* __restrict__ mean, int n) {
    int wv = (int)((blockIdx.x * blockDim.x + threadIdx.x) >> 6);
    int lane = threadIdx.x & 63;
    int sub = lane >> 5, sl = lane & 31;
    int node = wv * 2 + sub;
    if (node >= n) return;
    int h = sl >> 3;
    int start = node ? rp[node - 1] : 0;
    int end = rp[node];
    float ad = a_d[node * 4 + h];
    float z = __expf(lrelu(a_s[node * 4 + h] + ad));
    float acc[16];
    {
        uint4 u = *(const uint4*)(x8 + (size_t)node * 128 + sl * 4);
        float f[16];
        dec4(u.x, f); dec4(u.y, f + 4); dec4(u.z, f + 8); dec4(u.w, f + 12);
#pragma unroll
        for (int j = 0; j < 16; j++) acc[j] = z * f[j];
    }
    uint4 u0 = {}, u1 = {}, u2 = {};
    float A0 = 0.f, A1 = 0.f, A2 = 0.f;
    if (start < end) {
        int s = csr[start];
        u0 = *(const uint4*)(x8 + (size_t)s * 128 + sl * 4);
        A0 = a_s[s * 4 + h];
    }
    if (start + 1 < end) {
        int s = csr[start + 1];
        u1 = *(const uint4*)(x8 + (size_t)s * 128 + sl * 4);
        A1 = a_s[s * 4 + h];
    }
    if (start + 2 < end) {
        int s = csr[start + 2];
        u2 = *(const uint4*)(x8 + (size_t)s * 128 + sl * 4);
        A2 = a_s[s * 4 + h];
    }
    for (int e = start; e < end; e++) {
        uint4 uc = u0;
        float ac = A0;
        u0 = u1; A0 = A1;
        u1 = u2; A1 = A2;
        if (e + 3 < end) {
            int s = csr[e + 3];
            u2 = *(const uint4*)(x8 + (size_t)s * 128 + sl * 4);
            A2 = a_s[s * 4 + h];
        }
        float w = __expf(lrelu(ac + ad));
        z += w;
        float f[16];
        dec4(uc.x, f); dec4(uc.y, f + 4); dec4(uc.z, f + 8); dec4(uc.w, f + 12);
#pragma unroll
        for (int q = 0; q < 16; q++) acc[q] += w * f[q];
    }
    float scale = 0.25f / (z + 1e-16f);
#pragma unroll
    for (int j = 0; j < 16; j++) {
        float v = acc[j] * scale;
        v += __shfl_xor(v, 8, 64);
        v += __shfl_xor(v, 16, 64);
        acc[j] = v;
    }
    if ((sl & 24) == 0) {
        float4* op = (float4*)(mean + (size_t)node * 128 + sl * 16);
#pragma unroll
        for (int q = 0; q < 4; q++) {
            float4 o = {acc[4 * q], acc[4 * q + 1], acc[4 * q + 2], acc[4 * q + 3]};
            op[q] = o;
        }
    }
}

// per-graph mean pool (2G blocks), inline binary search on sorted batch
__global__ __launch_bounds__(128) void k_pool(const float* __restrict__ mean,
                                              const float* __restrict__ lin3,
                                              const float* __restrict__ b3,
                                              const int* __restrict__ bl,
                                              const int* __restrict__ br,
                                              int n, float* __restrict__ out) {
    int g = blockIdx.x, c = threadIdx.x;
    const int* b = (g < GG) ? bl : br;
    int tg = (g < GG) ? g : g - GG;
    int off = (g < GG) ? 0 : n;
    int s, e;
    { int lo = 0, hi = n; while (lo < hi) { int m = (lo + hi) >> 1; if (b[m] < tg) lo = m + 1; else hi = m; } s = lo; }
    { int lo = 0, hi = n; while (lo < hi) { int m = (lo + hi) >> 1; if (b[m] < tg + 1) lo = m + 1; else hi = m; } e = lo; }
    s += off; e += off;
    float acc = 0.f;
    for (int i = s; i < e; i++)
        acc += mean[(size_t)i * 128 + c] + lin3[(size_t)i * 128 + c];
    int cnt = e - s;
    out[(size_t)g * 128 + c] = cnt > 0 ? acc / (float)cnt + b3[c] : 0.f;
}

static inline int cdiv(int a, int b) { return (a + b - 1) / b; }

extern "C" void kernel_launch(void* const* d_in, const int* in_sizes, int n_in,
                              void* d_out, int out_size, void* d_ws, size_t ws_size,
                              hipStream_t stream) {
    const int* x_l = (const int*)d_in[0];
    const int* edge_l = (const int*)d_in[1];
    const int* batch_l = (const int*)d_in[2];
    const int* x_r = (const int*)d_in[3];
    const int* edge_r = (const int*)d_in[4];
    const int* batch_r = (const int*)d_in[5];
    const float* emb = (const float*)d_in[6];
    const float* W1 = (const float*)d_in[7];
    const float* as1 = (const float*)d_in[8];
    const float* ad1 = (const float*)d_in[9];
    const float* b1 = (const float*)d_in[10];
    const float* lw1 = (const float*)d_in[11];
    const float* lb1 = (const float*)d_in[12];
    const float* W2 = (const float*)d_in[13];
    const float* as2 = (const float*)d_in[14];
    const float* ad2 = (const float*)d_in[15];
    const float* b2 = (const float*)d_in[16];
    const float* lw2 = (const float*)d_in[17];
    const float* lb2 = (const float*)d_in[18];
    const float* W3 = (const float*)d_in[19];
    const float* as3 = (const float*)d_in[20];
    const float* ad3 = (const float*)d_in[21];
    const float* b3 = (const float*)d_in[22];
    const float* lw3 = (const float*)d_in[23];
    const float* lb3 = (const float*)d_in[24];

    const int n = in_sizes[0];       // 20000
    const int E = in_sizes[1] / 2;   // 320000
    const int N2 = 2 * n;

    float* MEAN = (float*)d_ws;                // [N2,128]
    float* L3 = MEAN + (size_t)N2 * 128;       // [N2,128] fp32 layer-3 skip
    float* a_s = L3 + (size_t)N2 * 128;        // [N2,4]
    float* a_d = a_s + (size_t)N2 * 4;
    int* rp = (int*)(a_d + (size_t)N2 * 4);    // [N2]
    int* csr = rp + N2;                        // [2E]
    __bf16* LINb = (__bf16*)(csr + 2 * E);     // [N2,256] bf16 skip (layers 1/2)
    unsigned char* X8a = (unsigned char*)(LINb + (size_t)N2 * 256);  // [N2,256] fp8
    unsigned char* X8b = X8a + (size_t)N2 * 256;                     // [N2,512] fp8
    __bf16* Abf = (__bf16*)(X8b + (size_t)N2 * 512);                 // [N2,256] GEMM A
    __bf16* B1t = Abf + (size_t)N2 * 256;  // 528 x 128
    __bf16* B2t = B1t + 528 * 128;         // 528 x 256
    __bf16* B3t = B2t + 528 * 256;         // 656 x 256

    const int TB = 256;
    dim3 blk(TB);

    // fused weight prep (1 dispatch)
    k_wprep<<<cdiv(370688, TB), blk, 0, stream>>>(W1, lw1, as1, ad1, W2, lw2, as2, ad2,
                                                  W3, lw3, as3, ad3, B1t, B2t, B3t);

    // combined CSR (once for all 3 layers, both sides)
    hipMemsetAsync(rp, 0, sizeof(int) * (size_t)N2, stream);
    k_hist2<<<cdiv(2 * E, TB), blk, 0, stream>>>(edge_l, edge_r, E, n, rp);
    k_scan<<<1, 1024, 0, stream>>>(rp, N2);
    k_fill2<<<cdiv(2 * E, TB), blk, 0, stream>>>(edge_l, edge_r, E, n, rp, csr);

    // ---- layer 1 (K=128, embed fused, Mx=256 -> fp8, Ml=256 -> bf16 lin) ----
    k_gemm_all<128, true, true><<<dim3(cdiv(N2, 64), 2), blk, 0, stream>>>(
        nullptr, x_l, x_r, emb, B1t, N2, n, 256, 256, X8a, 256, nullptr, LINb, 256, lb1, b1, a_s, a_d);
    k_agg12<<<cdiv(N2, 8), blk, 0, stream>>>(rp, csr, a_s, a_d, X8a, LINb, Abf, N2);

    // ---- layer 2 (K=256, Mx=256 -> fp8, Ml=256 -> bf16 lin) ----
    k_gemm_all<256, false, true><<<dim3(cdiv(N2, 64), 2), blk, 0, stream>>>(
        Abf, nullptr, nullptr, nullptr, B2t, N2, n, 256, 256, X8a, 256, nullptr, LINb, 256, lb2, b2, a_s, a_d);
    k_agg12<<<cdiv(N2, 8), blk, 0, stream>>>(rp, csr, a_s, a_d, X8a, LINb, Abf, N2);

    // ---- layer 3 (K=256, Mx=512 -> fp8, Ml=128 -> fp32 L3) ----
    k_gemm_all<256, false, false><<<dim3(cdiv(N2, 64), 2), blk, 0, stream>>>(
        Abf, nullptr, nullptr, nullptr, B3t, N2, n, 512, 128, X8b, 512, L3, nullptr, 128, lb3, nullptr, a_s, a_d);
    k_agg3<<<cdiv(N2, 8), blk, 0, stream>>>(rp, csr, a_s, a_d, (const unsigned int*)X8b, MEAN, N2);
    k_pool<<<2 * GG, 128, 0, stream>>>(MEAN, L3, b3, batch_l, batch_r, n, (float*)d_out);
}

// Round 14
// 446.431 us; speedup vs baseline: 1.3188x; 1.0848x over previous
//
#include <hip/hip_runtime.h>

#define GG 256

typedef __bf16 bf16x8 __attribute__((ext_vector_type(8)));
typedef __bf16 bf16x4 __attribute__((ext_vector_type(4)));
typedef float floatx4 __attribute__((ext_vector_type(4)));
typedef float f32x2 __attribute__((ext_vector_type(2)));

__device__ __forceinline__ float lrelu(float x) { return x > 0.f ? x : 0.2f * x; }

// column permutation within each 64-col group: compute-order -> consecutive true cols
__device__ __forceinline__ int permM(int m) {
    int g = m >> 6, q = m & 63;
    return (g << 6) | ((q & 3) << 4) | (q >> 2);
}

// ---- fused weight prep (B rows stored permuted; attn mini-tile unpermuted) ----
__device__ __forceinline__ void wt1(const float* __restrict__ B, __bf16* __restrict__ Bt,
                                    int K, int M, int idx) {
    int k = idx / M, m = idx - k * M;
    Bt[(size_t)permM(m) * K + k] = (__bf16)B[idx];
}
__device__ __forceinline__ void wattn1(const float* __restrict__ W,
                                       const float* __restrict__ as_,
                                       const float* __restrict__ ad_,
                                       __bf16* __restrict__ dst, int K, int C, int idx) {
    int j = idx / K, k = idx - j * K;
    float v = 0.f;
    if (j < 8) {
        int h = j & 3;
        const float* att = (j < 4) ? as_ : ad_;
        int M = 4 * C;
        for (int c = 0; c < C; c++) v += W[(size_t)k * M + h * C + c] * att[h * C + c];
    }
    dst[(size_t)j * K + k] = (__bf16)v;
}

__global__ void k_wprep(const float* W1, const float* lw1, const float* as1, const float* ad1,
                        const float* W2, const float* lw2, const float* as2, const float* ad2,
                        const float* W3, const float* lw3, const float* as3, const float* ad3,
                        __bf16* B1t, __bf16* B2t, __bf16* B3t) {
    int idx = blockIdx.x * blockDim.x + threadIdx.x;
    if (idx < 32768) { wt1(W1, B1t, 128, 256, idx); return; }
    idx -= 32768;
    if (idx < 32768) { wt1(lw1, B1t + 256 * 128, 128, 256, idx); return; }
    idx -= 32768;
    if (idx < 2048) { wattn1(W1, as1, ad1, B1t + 512 * 128, 128, 64, idx); return; }
    idx -= 2048;
    if (idx < 65536) { wt1(W2, B2t, 256, 256, idx); return; }
    idx -= 65536;
    if (idx < 65536) { wt1(lw2, B2t + 256 * 256, 256, 256, idx); return; }
    idx -= 65536;
    if (idx < 4096) { wattn1(W2, as2, ad2, B2t + 512 * 256, 256, 64, idx); return; }
    idx -= 4096;
    if (idx < 131072) { wt1(W3, B3t, 256, 512, idx); return; }
    idx -= 131072;
    if (idx < 32768) { wt1(lw3, B3t + 512 * 256, 256, 128, idx); return; }
    idx -= 32768;
    if (idx < 4096) { wattn1(W3, as3, ad3, B3t + 640 * 256, 256, 128, idx); return; }
}

// All-in-one GEMM (64-row blocks, register-pipelined B staging, packed epilogue).
template <int K, bool EMB, bool LINBF>
__global__ __launch_bounds__(256) void k_gemm_all(const __bf16* __restrict__ A,
                                                  const int* __restrict__ xl,
                                                  const int* __restrict__ xr,
                                                  const float* __restrict__ emb,
                                                  const __bf16* __restrict__ Bt,
                                                  int n, int n1, int Mx, int Ml,
                                                  unsigned char* __restrict__ x8, int ldx,
                                                  float* __restrict__ linf,
                                                  __bf16* __restrict__ linb, int ldl,
                                                  const float* __restrict__ bias1,
                                                  const float* __restrict__ bias2,
                                                  float* __restrict__ a_s,
                                                  float* __restrict__ a_d) {
    constexpr int KS = K / 32;
    constexpr int LDK = K + 8;
    constexpr int LPR = K / 8;
    constexpr int NCH = 64 * LPR / 256;
    __shared__ __bf16 S[64 * LDK];
    int tid = threadIdx.x;
    int wave = tid >> 6, lane = tid & 63;
    int row0 = blockIdx.x * 64;
#pragma unroll
    for (int c = 0; c < NCH; c++) {
        int i = tid + c * 256;
        int r = i / LPR, ko = (i - r * LPR) * 8;
        int gr = row0 + r;
        bf16x8 v = {};
        if (gr < n) {
            if (EMB) {
                int xi = (gr < n1) ? xl[gr] : xr[gr - n1];
                const float4* src = (const float4*)(emb + ((size_t)xi << 7) + ko);
                float4 q0 = src[0], q1 = src[1];
                v = bf16x8{(__bf16)q0.x, (__bf16)q0.y, (__bf16)q0.z, (__bf16)q0.w,
                           (__bf16)q1.x, (__bf16)q1.y, (__bf16)q1.z, (__bf16)q1.w};
            } else {
                v = *(const bf16x8*)(A + (size_t)gr * K + ko);
            }
        }
        *(bf16x8*)&S[r * LDK + ko] = v;
    }
    __syncthreads();
    int kOff = (lane >> 4) * 8;
    int colBase = lane & 15;
    bf16x8 af[KS];
#pragma unroll
    for (int ks = 0; ks < KS; ks++)
        af[ks] = *(const bf16x8*)&S[(wave * 16 + colBase) * LDK + ks * 32 + kOff];
    int Mtot = Mx + Ml;
    int gr0 = row0 + wave * 16 + ((lane >> 4) << 2);
    int half = (Mtot / 128) * 64;
    int c0beg = blockIdx.y * half;
    int T = half / 64;
    bf16x8 regs[NCH];
#pragma unroll
    for (int c = 0; c < NCH; c++) {
        int i = tid + c * 256;
        int r = i / LPR, ko = (i - r * LPR) * 8;
        regs[c] = *(const bf16x8*)(Bt + (size_t)(c0beg + r) * K + ko);
    }
    for (int t = 0; t < T; t++) {
        __syncthreads();
#pragma unroll
        for (int c = 0; c < NCH; c++) {
            int i = tid + c * 256;
            int r = i / LPR, ko = (i - r * LPR) * 8;
            *(bf16x8*)&S[r * LDK + ko] = regs[c];
        }
        if (t + 1 < T) {
            int c0n = c0beg + (t + 1) * 64;
#pragma unroll
            for (int c = 0; c < NCH; c++) {
                int i = tid + c * 256;
                int r = i / LPR, ko = (i - r * LPR) * 8;
                regs[c] = *(const bf16x8*)(Bt + (size_t)(c0n + r) * K + ko);
            }
        }
        __syncthreads();
        floatx4 acc[4] = {};
#pragma unroll
        for (int ct = 0; ct < 4; ct++) {
#pragma unroll
            for (int ks = 0; ks < KS; ks++) {
                bf16x8 bf = *(const bf16x8*)&S[(ct * 16 + colBase) * LDK + ks * 32 + kOff];
                acc[ct] = __builtin_amdgcn_mfma_f32_16x16x32_bf16(af[ks], bf, acc[ct], 0, 0, 0);
            }
        }
        int c0 = c0beg + t * 64;
        if (c0 < Mx) {  // packed fp8 dword store per row
#pragma unroll
            for (int r = 0; r < 4; r++) {
                int gr = gr0 + r;
                if (gr >= n) continue;
                int p = __builtin_amdgcn_cvt_pk_fp8_f32(acc[0][r], acc[1][r], 0, false);
                p = __builtin_amdgcn_cvt_pk_fp8_f32(acc[2][r], acc[3][r], p, true);
                *(unsigned int*)(x8 + (size_t)gr * ldx + c0 + colBase * 4) = (unsigned int)p;
            }
        } else {
            int c2 = c0 + colBase * 4 - Mx;
#pragma unroll
            for (int r = 0; r < 4; r++) {
                int gr = gr0 + r;
                if (gr >= n) continue;
                float v0 = acc[0][r] + bias1[c2 + 0];
                float v1 = acc[1][r] + bias1[c2 + 1];
                float v2 = acc[2][r] + bias1[c2 + 2];
                float v3 = acc[3][r] + bias1[c2 + 3];
                if (bias2) {
                    v0 += bias2[c2 + 0]; v1 += bias2[c2 + 1];
                    v2 += bias2[c2 + 2]; v3 += bias2[c2 + 3];
                }
                if (LINBF) {
                    bf16x4 o = {(__bf16)v0, (__bf16)v1, (__bf16)v2, (__bf16)v3};
                    *(bf16x4*)(linb + (size_t)gr * ldl + c2) = o;
                } else {
                    float4 o = {v0, v1, v2, v3};
                    *(float4*)(linf + (size_t)gr * ldl + c2) = o;
                }
            }
        }
    }
    if (blockIdx.y == 1) {  // attn mini-tile (unpermuted rows)
        floatx4 acc = {};
        const __bf16* bp = Bt + (size_t)(Mtot + colBase) * K + kOff;
#pragma unroll
        for (int ks = 0; ks < KS; ks++) {
            bf16x8 bf = *(const bf16x8*)(bp + ks * 32);
            acc = __builtin_amdgcn_mfma_f32_16x16x32_bf16(af[ks], bf, acc, 0, 0, 0);
        }
        if (colBase < 8) {
            float* dst = (colBase < 4) ? a_s : a_d;
            int h = colBase & 3;
#pragma unroll
            for (int r = 0; r < 4; r++) {
                int gr = gr0 + r;
                if (gr < n) dst[gr * 4 + h] = acc[r];
            }
        }
    }
}

// ---- combined-CSR build (side-1 ids offset by n) ----
__global__ void k_hist2(const int* __restrict__ el, const int* __restrict__ er,
                        int E, int n, int* __restrict__ deg) {
    int e = blockIdx.x * blockDim.x + threadIdx.x;
    if (e >= 2 * E) return;
    int d = (e < E) ? el[E + e] : er[E + (e - E)] + n;
    atomicAdd(&deg[d], 1);
}

// ---- 3-pass parallel exclusive scan over rp[0..n) ----
// pass 1: block-local exclusive scan (1024 elems/block), block total -> part
__global__ __launch_bounds__(1024) void k_scan1(int* __restrict__ rp, int n,
                                                int* __restrict__ part) {
    __shared__ int wsum[16];
    int i = blockIdx.x * 1024 + threadIdx.x;
    int lane = threadIdx.x & 63, wid = threadIdx.x >> 6;
    int v = (i < n) ? rp[i] : 0;
    int inc = v;
#pragma unroll
    for (int off = 1; off < 64; off <<= 1) {
        int t = __shfl_up(inc, off, 64);
        if (lane >= off) inc += t;
    }
    if (lane == 63) wsum[wid] = inc;
    __syncthreads();
    if (wid == 0) {
        int wv = (lane < 16) ? wsum[lane] : 0;
        int winc = wv;
#pragma unroll
        for (int off = 1; off < 16; off <<= 1) {
            int t = __shfl_up(winc, off, 64);
            if (lane >= off) winc += t;
        }
        if (lane < 16) wsum[lane] = winc - wv;  // exclusive wave offsets
        if (lane == 15) part[blockIdx.x] = winc;  // block total
    }
    __syncthreads();
    if (i < n) rp[i] = wsum[wid] + (inc - v);  // block-local exclusive
}

// pass 2: one wave exclusive-scans part[nb] (nb <= 64)
__global__ void k_scan2(int* __restrict__ part, int nb) {
    int lane = threadIdx.x;
    int v = (lane < nb) ? part[lane] : 0;
    int inc = v;
#pragma unroll
    for (int off = 1; off < 64; off <<= 1) {
        int t = __shfl_up(inc, off, 64);
        if (lane >= off) inc += t;
    }
    if (lane < nb) part[lane] = inc - v;  // exclusive
}

// pass 3: add block offsets
__global__ __launch_bounds__(1024) void k_scan3(int* __restrict__ rp, int n,
                                                const int* __restrict__ part) {
    int i = blockIdx.x * 1024 + threadIdx.x;
    if (i < n) rp[i] += part[blockIdx.x];
}

__global__ void k_fill2(const int* __restrict__ el, const int* __restrict__ er,
                        int E, int n, int* __restrict__ rp, int* __restrict__ csr) {
    int e = blockIdx.x * blockDim.x + threadIdx.x;
    if (e >= 2 * E) return;
    int d, s;
    if (e < E) { s = el[e]; d = el[E + e]; }
    else       { s = er[e - E] + n; d = er[E + (e - E)] + n; }
    int pos = atomicAdd(&rp[d], 1);
    csr[pos] = s;
}

__device__ __forceinline__ void dec4(unsigned int u, float* f) {
    f32x2 a = __builtin_amdgcn_cvt_pk_f32_fp8(u, false);
    f32x2 b = __builtin_amdgcn_cvt_pk_f32_fp8(u, true);
    f[0] = a[0]; f[1] = a[1]; f[2] = b[0]; f[3] = b[1];
}

// Layers 1/2 aggregation on fp8 rows (256 B): 2 nodes/wave, depth-3 prefetch.
__global__ __launch_bounds__(256) void k_agg12(const int* __restrict__ rp,
                                               const int* __restrict__ csr,
                                               const float* __restrict__ a_s,
                                               const float* __restrict__ a_d,
                                               const unsigned char* __restrict__ x8,
                                               const __bf16* __restrict__ lin,
                                               __bf16* __restrict__ out_bf, int n) {
    int wv = (int)((blockIdx.x * blockDim.x + threadIdx.x) >> 6);
    int lane = threadIdx.x & 63;
    int sub = lane >> 5, sl = lane & 31;
    int node = wv * 2 + sub;
    if (node >= n) return;
    int c0 = sl * 8;
    int h = sl >> 3;
    int start = node ? rp[node - 1] : 0;
    int end = rp[node];
    float ad = a_d[node * 4 + h];
    float z = __expf(lrelu(a_s[node * 4 + h] + ad));
    float acc[8];
    {
        uint2 u = *(const uint2*)(x8 + (size_t)node * 256 + c0);
        float f[8];
        dec4(u.x, f); dec4(u.y, f + 4);
#pragma unroll
        for (int j = 0; j < 8; j++) acc[j] = z * f[j];
    }
    uint2 u0 = {}, u1 = {}, u2 = {};
    float A0 = 0.f, A1 = 0.f, A2 = 0.f;
    if (start < end) {
        int s = csr[start];
        u0 = *(const uint2*)(x8 + (size_t)s * 256 + c0);
        A0 = a_s[s * 4 + h];
    }
    if (start + 1 < end) {
        int s = csr[start + 1];
        u1 = *(const uint2*)(x8 + (size_t)s * 256 + c0);
        A1 = a_s[s * 4 + h];
    }
    if (start + 2 < end) {
        int s = csr[start + 2];
        u2 = *(const uint2*)(x8 + (size_t)s * 256 + c0);
        A2 = a_s[s * 4 + h];
    }
    for (int e = start; e < end; e++) {
        uint2 uc = u0;
        float ac = A0;
        u0 = u1; A0 = A1;
        u1 = u2; A1 = A2;
        if (e + 3 < end) {
            int s = csr[e + 3];
            u2 = *(const uint2*)(x8 + (size_t)s * 256 + c0);
            A2 = a_s[s * 4 + h];
        }
        float w = __expf(lrelu(ac + ad));
        z += w;
        float f[8];
        dec4(uc.x, f); dec4(uc.y, f + 4);
#pragma unroll
        for (int q = 0; q < 8; q++) acc[q] += w * f[q];
    }
    float inv = 1.f / (z + 1e-16f);
    bf16x8 l = *(const bf16x8*)(lin + (size_t)node * 256 + c0);
    bf16x8 r;
#pragma unroll
    for (int j = 0; j < 8; j++)
        r[j] = (__bf16)fmaxf(acc[j] * inv + (float)l[j], 0.f);
    *(bf16x8*)(out_bf + (size_t)node * 256 + c0) = r;
}

// Layer-3 aggregation (HC=512) on fp8 rows; 2 nodes/wave; depth-3 prefetch;
// head-mean via shfl -> mean[n,128]
__global__ __launch_bounds__(256) void k_agg3(const int* __restrict__ rp,
                                              const int* __restrict__ csr,
                                              const float* __restrict__ a_s,
                                              const float* __restrict__ a_d,
                                              const unsigned int* __restrict__ x8,
                                              float* __restrict__ mean, int n) {
    int wv = (int)((blockIdx.x * blockDim.x + threadIdx.x) >> 6);
    int lane = threadIdx.x & 63;
    int sub = lane >> 5, sl = lane & 31;
    int node = wv * 2 + sub;
    if (node >= n) return;
    int h = sl >> 3;
    int start = node ? rp[node - 1] : 0;
    int end = rp[node];
    float ad = a_d[node * 4 + h];
    float z = __expf(lrelu(a_s[node * 4 + h] + ad));
    float acc[16];
    {
        uint4 u = *(const uint4*)(x8 + (size_t)node * 128 + sl * 4);
        float f[16];
        dec4(u.x, f); dec4(u.y, f + 4); dec4(u.z, f + 8); dec4(u.w, f + 12);
#pragma unroll
        for (int j = 0; j < 16; j++) acc[j] = z * f[j];
    }
    uint4 u0 = {}, u1 = {}, u2 = {};
    float A0 = 0.f, A1 = 0.f, A2 = 0.f;
    if (start < end) {
        int s = csr[start];
        u0 = *(const uint4*)(x8 + (size_t)s * 128 + sl * 4);
        A0 = a_s[s * 4 + h];
    }
    if (start + 1 < end) {
        int s = csr[start + 1];
        u1 = *(const uint4*)(x8 + (size_t)s * 128 + sl * 4);
        A1 = a_s[s * 4 + h];
    }
    if (start + 2 < end) {
        int s = csr[start + 2];
        u2 = *(const uint4*)(x8 + (size_t)s * 128 + sl * 4);
        A2 = a_s[s * 4 + h];
    }
    for (int e = start; e < end; e++) {
        uint4 uc = u0;
        float ac = A0;
        u0 = u1; A0 = A1;
        u1 = u2; A1 = A2;
        if (e + 3 < end) {
            int s = csr[e + 3];
            u2 = *(const uint4*)(x8 + (size_t)s * 128 + sl * 4);
            A2 = a_s[s * 4 + h];
        }
        float w = __expf(lrelu(ac + ad));
        z += w;
        float f[16];
        dec4(uc.x, f); dec4(uc.y, f + 4); dec4(uc.z, f + 8); dec4(uc.w, f + 12);
#pragma unroll
        for (int q = 0; q < 16; q++) acc[q] += w * f[q];
    }
    float scale = 0.25f / (z + 1e-16f);
#pragma unroll
    for (int j = 0; j < 16; j++) {
        float v = acc[j] * scale;
        v += __shfl_xor(v, 8, 64);
        v += __shfl_xor(v, 16, 64);
        acc[j] = v;
    }
    if ((sl & 24) == 0) {
        float4* op = (float4*)(mean + (size_t)node * 128 + sl * 16);
#pragma unroll
        for (int q = 0; q < 4; q++) {
            float4 o = {acc[4 * q], acc[4 * q + 1], acc[4 * q + 2], acc[4 * q + 3]};
            op[q] = o;
        }
    }
}

// per-graph mean pool (2G blocks), inline binary search on sorted batch
__global__ __launch_bounds__(128) void k_pool(const float* __restrict__ mean,
                                              const float* __restrict__ lin3,
                                              const float* __restrict__ b3,
                                              const int* __restrict__ bl,
                                              const int* __restrict__ br,
                                              int n, float* __restrict__ out) {
    int g = blockIdx.x, c = threadIdx.x;
    const int* b = (g < GG) ? bl : br;
    int tg = (g < GG) ? g : g - GG;
    int off = (g < GG) ? 0 : n;
    int s, e;
    { int lo = 0, hi = n; while (lo < hi) { int m = (lo + hi) >> 1; if (b[m] < tg) lo = m + 1; else hi = m; } s = lo; }
    { int lo = 0, hi = n; while (lo < hi) { int m = (lo + hi) >> 1; if (b[m] < tg + 1) lo = m + 1; else hi = m; } e = lo; }
    s += off; e += off;
    float acc = 0.f;
    for (int i = s; i < e; i++)
        acc += mean[(size_t)i * 128 + c] + lin3[(size_t)i * 128 + c];
    int cnt = e - s;
    out[(size_t)g * 128 + c] = cnt > 0 ? acc / (float)cnt + b3[c] : 0.f;
}

static inline int cdiv(int a, int b) { return (a + b - 1) / b; }

extern "C" void kernel_launch(void* const* d_in, const int* in_sizes, int n_in,
                              void* d_out, int out_size, void* d_ws, size_t ws_size,
                              hipStream_t stream) {
    const int* x_l = (const int*)d_in[0];
    const int* edge_l = (const int*)d_in[1];
    const int* batch_l = (const int*)d_in[2];
    const int* x_r = (const int*)d_in[3];
    const int* edge_r = (const int*)d_in[4];
    const int* batch_r = (const int*)d_in[5];
    const float* emb = (const float*)d_in[6];
    const float* W1 = (const float*)d_in[7];
    const float* as1 = (const float*)d_in[8];
    const float* ad1 = (const float*)d_in[9];
    const float* b1 = (const float*)d_in[10];
    const float* lw1 = (const float*)d_in[11];
    const float* lb1 = (const float*)d_in[12];
    const float* W2 = (const float*)d_in[13];
    const float* as2 = (const float*)d_in[14];
    const float* ad2 = (const float*)d_in[15];
    const float* b2 = (const float*)d_in[16];
    const float* lw2 = (const float*)d_in[17];
    const float* lb2 = (const float*)d_in[18];
    const float* W3 = (const float*)d_in[19];
    const float* as3 = (const float*)d_in[20];
    const float* ad3 = (const float*)d_in[21];
    const float* b3 = (const float*)d_in[22];
    const float* lw3 = (const float*)d_in[23];
    const float* lb3 = (const float*)d_in[24];

    const int n = in_sizes[0];       // 20000
    const int E = in_sizes[1] / 2;   // 320000
    const int N2 = 2 * n;
    const int NB = cdiv(N2, 1024);   // scan blocks (40 <= 64)

    float* MEAN = (float*)d_ws;                // [N2,128]
    float* L3 = MEAN + (size_t)N2 * 128;       // [N2,128] fp32 layer-3 skip
    float* a_s = L3 + (size_t)N2 * 128;        // [N2,4]
    float* a_d = a_s + (size_t)N2 * 4;
    int* rp = (int*)(a_d + (size_t)N2 * 4);    // [N2]
    int* csr = rp + N2;                        // [2E]
    int* part = csr + 2 * E;                   // [64] scan partials
    __bf16* LINb = (__bf16*)(part + 64);       // [N2,256] bf16 skip (layers 1/2)
    unsigned char* X8a = (unsigned char*)(LINb + (size_t)N2 * 256);  // [N2,256] fp8
    unsigned char* X8b = X8a + (size_t)N2 * 256;                     // [N2,512] fp8
    __bf16* Abf = (__bf16*)(X8b + (size_t)N2 * 512);                 // [N2,256] GEMM A
    __bf16* B1t = Abf + (size_t)N2 * 256;  // 528 x 128
    __bf16* B2t = B1t + 528 * 128;         // 528 x 256
    __bf16* B3t = B2t + 528 * 256;         // 656 x 256

    const int TB = 256;
    dim3 blk(TB);

    // fused weight prep (1 dispatch)
    k_wprep<<<cdiv(370688, TB), blk, 0, stream>>>(W1, lw1, as1, ad1, W2, lw2, as2, ad2,
                                                  W3, lw3, as3, ad3, B1t, B2t, B3t);

    // combined CSR (once for all 3 layers, both sides), parallel scan
    hipMemsetAsync(rp, 0, sizeof(int) * (size_t)N2, stream);
    k_hist2<<<cdiv(2 * E, TB), blk, 0, stream>>>(edge_l, edge_r, E, n, rp);
    k_scan1<<<NB, 1024, 0, stream>>>(rp, N2, part);
    k_scan2<<<1, 64, 0, stream>>>(part, NB);
    k_scan3<<<NB, 1024, 0, stream>>>(rp, N2, part);
    k_fill2<<<cdiv(2 * E, TB), blk, 0, stream>>>(edge_l, edge_r, E, n, rp, csr);

    // ---- layer 1 (K=128, embed fused, Mx=256 -> fp8, Ml=256 -> bf16 lin) ----
    k_gemm_all<128, true, true><<<dim3(cdiv(N2, 64), 2), blk, 0, stream>>>(
        nullptr, x_l, x_r, emb, B1t, N2, n, 256, 256, X8a, 256, nullptr, LINb, 256, lb1, b1, a_s, a_d);
    k_agg12<<<cdiv(N2, 8), blk, 0, stream>>>(rp, csr, a_s, a_d, X8a, LINb, Abf, N2);

    // ---- layer 2 (K=256, Mx=256 -> fp8, Ml=256 -> bf16 lin) ----
    k_gemm_all<256, false, true><<<dim3(cdiv(N2, 64), 2), blk, 0, stream>>>(
        Abf, nullptr, nullptr, nullptr, B2t, N2, n, 256, 256, X8a, 256, nullptr, LINb, 256, lb2, b2, a_s, a_d);
    k_agg12<<<cdiv(N2, 8), blk, 0, stream>>>(rp, csr, a_s, a_d, X8a, LINb, Abf, N2);

    // ---- layer 3 (K=256, Mx=512 -> fp8, Ml=128 -> fp32 L3) ----
    k_gemm_all<256, false, false><<<dim3(cdiv(N2, 64), 2), blk, 0, stream>>>(
        Abf, nullptr, nullptr, nullptr, B3t, N2, n, 512, 128, X8b, 512, L3, nullptr, 128, lb3, nullptr, a_s, a_d);
    k_agg3<<<cdiv(N2, 8), blk, 0, stream>>>(rp, csr, a_s, a_d, (const unsigned int*)X8b, MEAN, N2);
    k_pool<<<2 * GG, 128, 0, stream>>>(MEAN, L3, b3, batch_l, batch_r, n, (float*)d_out);
}